// Round 15
// baseline (192.039 us; speedup 1.0000x reference)
//
#include <hip/hip_runtime.h>
#include <hip/hip_bf16.h>
#include <stdint.h>

typedef __attribute__((ext_vector_type(8))) __bf16 bf16x8;
typedef __attribute__((ext_vector_type(4))) __bf16 bf16x4;
typedef __attribute__((ext_vector_type(4))) float f32x4;

#define HN 16
#define DM 1024
#define GQ 128
#define SEQ 4096
#define BLK 512
#define SCALE 0.125f
#define LOG2E 1.44269504f
#define QSCALE2 0.18033688f  /* SCALE * log2(e) */
#define THR2 11.5415f        /* 8 * log2(e): same e^8 bound on P */
#define NCHUNK 11

#define GLL16(g, l) __builtin_amdgcn_global_load_lds( \
    (__attribute__((address_space(1))) void*)(g), \
    (__attribute__((address_space(3))) void*)(l), 16, 0, 0)

// ---------------- merged cast: weights + token X + global X ----------------
__global__ void cast_all(const float* __restrict__ w0, const float* __restrict__ w1,
                         const float* __restrict__ w2, const float* __restrict__ w3,
                         const float* __restrict__ Xt, const float* __restrict__ Xg,
                         __bf16* __restrict__ Wb, __bf16* __restrict__ XB) {
  int bid = blockIdx.x;
  const float* src;
  __bf16* dst;
  int t;
  if (bid < 4096) {                      // 4 weights x 1024 blocks
    int wi = bid >> 10;
    const float* srcs[4] = {w0, w1, w2, w3};
    src = srcs[wi];
    t = (bid & 1023) * 256 + threadIdx.x;
    dst = Wb + (size_t)wi * (size_t)(DM * DM);
  } else if (bid < 4096 + 8192) {        // token hidden states
    src = Xt;
    t = (bid - 4096) * 256 + threadIdx.x;
    dst = XB;
  } else {                               // global hidden states (256 blocks)
    src = Xg;
    t = (bid - 12288) * 256 + threadIdx.x;
    dst = XB + (size_t)8192 * DM;
  }
  float4 v = ((const float4*)src)[t];
  bf16x4 o = {(__bf16)v.x, (__bf16)v.y, (__bf16)v.z, (__bf16)v.w};
  ((bf16x4*)dst)[t] = o;
}

// ---------------- 64x128x64 QKV GEMM: round-14 granularity lesson ----------
// Same K-loop recipe (single-buffer, vmcnt(0)+barrier, XOR-8 zero-conflict
// swizzle) at half the M-tile: 3168 half-duration blocks, 24 KB LDS -> 6
// blocks/CU. Fixes the 1.55-generation tail that capped round-14's gemmqkv
// at 30% MfmaUtil (same mechanism as round-14's attn granularity win).
__global__ __launch_bounds__(256, 6) void gemmqkv(
    const __bf16* __restrict__ A, const __bf16* __restrict__ W,
    __bf16* __restrict__ Qt, __bf16* __restrict__ Kt, __bf16* __restrict__ VtT,
    __bf16* __restrict__ Qg, __bf16* __restrict__ Kg, __bf16* __restrict__ VgT,
    int NT) {
  __shared__ __bf16 S[12288];  // K-loop: As(4096)|Bs(8192); epilogue: 64x128 C
  __bf16* As = S;
  __bf16* Bs = S + 4096;
  int tid = threadIdx.x;
  int lane = tid & 63, wid = tid >> 6;
  int lr = lane & 15, lh = lane >> 4;
  int wm = wid >> 1, wn = wid & 1;  // wave: 32 rows x 64 cols of 64x128 tile

  int nwg = gridDim.x;
  int q = nwg >> 3, r = nwg & 7;
  int xcd = blockIdx.x & 7, loc = blockIdx.x >> 3;
  int swz = (xcd < r ? xcd * (q + 1) : r * (q + 1) + (xcd - r) * q) + loc;
  int bm = swz / NT, bn = swz - bm * NT;
  long m0 = (long)bm * 64, n0 = (long)bn * 128;
  const __bf16* Ab = A + m0 * 1024;
  const __bf16* Wb2 = W + n0 * 1024;

  int srow = tid >> 3;                          // 0..31, 8 threads/row
  int scol = (((tid & 7) ^ (srow & 7)) << 3);   // pre-swizzled source granule

  f32x4 acc[2][4];
#pragma unroll
  for (int i = 0; i < 2; ++i)
#pragma unroll
    for (int j = 0; j < 4; ++j) acc[i][j] = (f32x4){0.f, 0.f, 0.f, 0.f};

#pragma unroll 1
  for (int kt = 0; kt < 16; ++kt) {
    int k0 = kt * 64;
#pragma unroll
    for (int c = 0; c < 2; ++c) {
      int row = srow + c * 32;
      GLL16(Ab + (long)row * 1024 + k0 + scol, &As[(c * 256 + tid) * 8]);
    }
#pragma unroll
    for (int c = 0; c < 4; ++c) {
      int row = srow + c * 32;
      GLL16(Wb2 + (long)row * 1024 + k0 + scol, &Bs[(c * 256 + tid) * 8]);
    }
    asm volatile("s_waitcnt vmcnt(0)" ::: "memory");
    __syncthreads();

#pragma unroll
    for (int ks = 0; ks < 2; ++ks) {
      bf16x8 af[2], bfr[4];
#pragma unroll
      for (int i = 0; i < 2; ++i) {
        int rr = wm * 32 + i * 16 + lr;
        af[i] = *(const bf16x8*)&As[rr * 64 + (((ks * 4 + lh) ^ (rr & 7)) << 3)];
      }
#pragma unroll
      for (int j = 0; j < 4; ++j) {
        int cc = wn * 64 + j * 16 + lr;
        bfr[j] = *(const bf16x8*)&Bs[cc * 64 + (((ks * 4 + lh) ^ (cc & 7)) << 3)];
      }
#pragma unroll
      for (int i = 0; i < 2; ++i)
#pragma unroll
        for (int j = 0; j < 4; ++j)
          acc[i][j] = __builtin_amdgcn_mfma_f32_16x16x32_bf16(af[i], bfr[j],
                                                              acc[i][j], 0, 0, 0);
    }
    __syncthreads();
  }

  int z = (int)(n0 >> 10);           // 0=Q 1=K 2=V (constant per block)
  float qs = (z == 0) ? QSCALE2 : 1.0f;

  // ---- epilogue: C(64x128) -> LDS (swizzled) -> coalesced stores ----
  __bf16* Cl = S;
#pragma unroll
  for (int i = 0; i < 2; ++i)
#pragma unroll
    for (int j = 0; j < 4; ++j) {
      int col = wn * 64 + j * 16 + lr;
      int cg = col >> 3, ce = col & 7;
#pragma unroll
      for (int jj = 0; jj < 4; ++jj) {
        int row = wm * 32 + i * 16 + lh * 4 + jj;
        Cl[row * 128 + ((cg ^ (row & 7)) << 3) + ce] = (__bf16)(acc[i][j][jj] * qs);
      }
    }
  __syncthreads();

  int hbase = ((int)n0 & 1023) >> 6;
  int tok = m0 < 8192;

  if (z < 2) {
    // 4 threads per row: part selects head-seg (part>>1) and 32-elem half
    int row = tid >> 2, part = tid & 3, seg = part >> 1;
    long grow = m0 + row;
    __bf16* dst;
    if (tok) {
      long bh = (grow >> 12) * HN + hbase + seg;
      dst = (z == 0 ? Qt : Kt) + (bh * SEQ + (grow & 4095)) * 64;
    } else {
      int gr = (int)(grow - 8192);
      long bh = (long)(gr >> 7) * HN + hbase + seg;
      dst = (z == 0 ? Qg : Kg) + (bh * GQ + (gr & 127)) * 64;
    }
#pragma unroll
    for (int k = 0; k < 4; ++k) {
      int gg = (part & 1) * 4 + k;      // granule within the head-seg (0..7)
      int g8 = seg * 8 + gg;            // granule within the 128-col row
      bf16x8 v = *(const bf16x8*)&Cl[row * 128 + ((g8 ^ (row & 7)) << 3)];
      *(bf16x8*)(dst + gg * 8) = v;
    }
  } else {
    int colL = tid >> 1, half = tid & 1;  // 2 threads/col: rows half*32..+31
    int h = hbase + (colL >> 6), f = colL & 63;
    int cg = colL >> 3, ce = colL & 7;
    __bf16* dst;
    if (tok) {
      long bh = (m0 >> 12) * HN + h;
      dst = VtT + (bh * 64 + f) * SEQ + (int)(m0 & 4095) + half * 32;
    } else {
      long gr0 = m0 - 8192;
      long bh = (gr0 >> 7) * HN + h;
      dst = VgT + (bh * 64 + f) * GQ + (int)(gr0 & 127) + half * 32;
    }
#pragma unroll
    for (int c8 = 0; c8 < 4; ++c8) {
      bf16x8 v;
#pragma unroll
      for (int e = 0; e < 8; ++e) {
        int rr = half * 32 + c8 * 8 + e;
        v[e] = Cl[rr * 128 + ((cg ^ (rr & 7)) << 3) + ce];
      }
      *(bf16x8*)(dst + c8 * 8) = v;
    }
  }
}

// ---------------- 128x128x64 GEMM (round-3 proven) for output projection ---
__global__ __launch_bounds__(256, 4) void gemm128(
    const __bf16* __restrict__ A, const __bf16* __restrict__ W,
    float* __restrict__ Cf, int NT) {
  __shared__ __bf16 As[128 * 64];
  __shared__ __bf16 Bs[128 * 64];
  int tid = threadIdx.x;
  int lane = tid & 63, wid = tid >> 6;
  int lr = lane & 15, lh = lane >> 4;
  int wm = wid >> 1, wn = wid & 1;

  int nwg = gridDim.x;
  int q = nwg >> 3, r = nwg & 7;
  int xcd = blockIdx.x & 7, loc = blockIdx.x >> 3;
  int swz = (xcd < r ? xcd * (q + 1) : r * (q + 1) + (xcd - r) * q) + loc;
  int bm = swz / NT, bn = swz - bm * NT;
  long m0 = (long)bm * 128, n0 = (long)bn * 128;
  const __bf16* Ab = A + m0 * 1024;
  const __bf16* Wb2 = W + n0 * 1024;

  int srow = tid >> 3;
  int scol = (((tid & 7) ^ (srow & 7)) << 3);

  f32x4 acc[4][4];
#pragma unroll
  for (int i = 0; i < 4; ++i)
#pragma unroll
    for (int j = 0; j < 4; ++j) acc[i][j] = (f32x4){0.f, 0.f, 0.f, 0.f};

#pragma unroll 1
  for (int kt = 0; kt < 16; ++kt) {
    int k0 = kt * 64;
#pragma unroll
    for (int c = 0; c < 4; ++c) {
      int row = srow + c * 32;
      GLL16(Ab + (long)row * 1024 + k0 + scol, &As[(c * 256 + tid) * 8]);
    }
#pragma unroll
    for (int c = 0; c < 4; ++c) {
      int row = srow + c * 32;
      GLL16(Wb2 + (long)row * 1024 + k0 + scol, &Bs[(c * 256 + tid) * 8]);
    }
    asm volatile("s_waitcnt vmcnt(0)" ::: "memory");
    __syncthreads();

#pragma unroll
    for (int ks = 0; ks < 2; ++ks) {
      bf16x8 af[4], bfr[4];
#pragma unroll
      for (int i = 0; i < 4; ++i) {
        int rr = wm * 64 + i * 16 + lr;
        af[i] = *(const bf16x8*)&As[rr * 64 + (((ks * 4 + lh) ^ (rr & 7)) << 3)];
        int cc = wn * 64 + i * 16 + lr;
        bfr[i] = *(const bf16x8*)&Bs[cc * 64 + (((ks * 4 + lh) ^ (cc & 7)) << 3)];
      }
#pragma unroll
      for (int i = 0; i < 4; ++i)
#pragma unroll
        for (int j = 0; j < 4; ++j)
          acc[i][j] = __builtin_amdgcn_mfma_f32_16x16x32_bf16(af[i], bfr[j],
                                                              acc[i][j], 0, 0, 0);
    }
    __syncthreads();
  }

#pragma unroll
  for (int i = 0; i < 4; ++i) {
    long row0 = m0 + wm * 64 + i * 16 + lh * 4;
#pragma unroll
    for (int j = 0; j < 4; ++j) {
      int col = (int)n0 + wn * 64 + j * 16 + lr;
#pragma unroll
      for (int jj = 0; jj < 4; ++jj) Cf[(row0 + jj) * 1024 + col] = acc[i][j][jj];
    }
  }
}

// --- fused flash attention: 64 q-rows/block (round-14, proven) --------------
__global__ __launch_bounds__(256) void attn_kernel(
    const __bf16* __restrict__ Qt, const __bf16* __restrict__ Qg,
    const __bf16* __restrict__ Kg, const __bf16* __restrict__ VgT,
    const __bf16* __restrict__ Kt, const __bf16* __restrict__ VtT,
    const float* __restrict__ mask,
    __bf16* __restrict__ AL, float* __restrict__ Opart, float* __restrict__ Ml) {
  __shared__ __bf16 Ks[2][64 * 64];
  __shared__ __bf16 Vs[2][64 * 64];
  __shared__ __bf16 Ps[64 * 64];

  int hw = blockIdx.x;
  int bid = ((hw >> 6) << 6) + ((hw & 7) << 3) + ((hw >> 3) & 7);

  int tid = threadIdx.x, wid = tid >> 6, lane = tid & 63;
  int lr = lane & 15, lh = lane >> 4;

  int isLocal = bid < 2048;
  int unit, q0, tgoff, tokbase, ntiles, pidx = 0;
  if (isLocal) {
    unit = bid >> 6;
    q0 = (bid & 63) << 6;           // 64 q-rows per block
    tgoff = 0;
    tokbase = q0 & ~(BLK - 1);
    ntiles = 10;
  } else {
    int x = bid - 2048;
    int uh = x / NCHUNK;            // unit*2 + row-half
    int chunk = x - uh * NCHUNK;
    unit = uh >> 1;
    q0 = (uh & 1) << 6;             // 0 or 64 within the 128 global q-rows
    tgoff = chunk * 6;
    tokbase = 0;
    ntiles = 6;
    pidx = x;
  }
  int b = unit >> 4, h = unit & 15;
  long bh = unit;
  const __bf16* Qbase = isLocal ? Qt + (bh * SEQ + q0) * 64
                                : Qg + (bh * GQ + q0) * 64;

  bf16x8 qf[2];
#pragma unroll
  for (int ks = 0; ks < 2; ks++)
    qf[ks] = *(const bf16x8*)&Qbase[(wid * 16 + lr) * 64 + ks * 32 + lh * 8];

  float mrun = -__builtin_inff(), lrun = 0.f;
  f32x4 oacc[4];
#pragma unroll
  for (int n = 0; n < 4; n++) oacc[n] = (f32x4){0.f, 0.f, 0.f, 0.f};

  int rx = lane & 7;  // 3-bit read-side granule XOR (read rows = lr mod 8)
  int scol = (((lane & 7) ^ (lane >> 3)) << 3);
  int prow = wid * 16 + lr;  // P row (prow&7 == lr&7)

  auto stage = [&](int t, int bb) {
    int tg = t + tgoff;
    int glob = tg < 2;
    int kpos0 = glob ? tg * 64 : tokbase + (tg - 2) * 64;
    const __bf16* Kp = glob ? Kg + (bh * GQ + kpos0) * 64 : Kt + (bh * SEQ + kpos0) * 64;
    const __bf16* Vp = glob ? VgT + bh * 64 * GQ + kpos0 : VtT + bh * 64 * SEQ + kpos0;
    long vstr = glob ? GQ : SEQ;
#pragma unroll
    for (int s = 0; s < 2; ++s) {
      int r = s * 32 + wid * 8 + (lane >> 3);  // r&7 == lane>>3
      GLL16(Kp + (long)r * 64 + scol, &Ks[bb][(s * 256 + wid * 64) * 8]);
      GLL16(Vp + (long)r * vstr + scol, &Vs[bb][(s * 256 + wid * 64) * 8]);
    }
  };

  stage(0, 0);

  for (int t = 0; t < ntiles; ++t) {
    int bb = t & 1;
    int tg = t + tgoff;
    int glob = tg < 2;
    int kpos0 = glob ? tg * 64 : tokbase + (tg - 2) * 64;

    __syncthreads();
    if (t + 1 < ntiles) stage(t + 1, bb ^ 1);

    f32x4 sacc[4];
#pragma unroll
    for (int n = 0; n < 4; n++) sacc[n] = (f32x4){0.f, 0.f, 0.f, 0.f};
#pragma unroll
    for (int ks = 0; ks < 2; ++ks) {
      bf16x8 kf[4];
#pragma unroll
      for (int n = 0; n < 4; n++)
        kf[n] = *(const bf16x8*)&Ks[bb][(n * 16 + lr) * 64 + (((ks * 4 + lh) ^ rx) << 3)];
#pragma unroll
      for (int n = 0; n < 4; n++)
        sacc[n] = __builtin_amdgcn_mfma_f32_16x16x32_bf16(kf[n], qf[ks], sacc[n], 0, 0, 0);
    }

    float4 mk[4];
    if (glob) {
#pragma unroll
      for (int n = 0; n < 4; n++) mk[n] = (float4){0.f, 0.f, 0.f, 0.f};
    } else {
#pragma unroll
      for (int n = 0; n < 4; n++) {
        float4 t4 = *(const float4*)&mask[(long)b * SEQ + kpos0 + n * 16 + lh * 4];
        mk[n] = (float4){t4.x * LOG2E, t4.y * LOG2E, t4.z * LOG2E, t4.w * LOG2E};
      }
    }

    // mask add, per-row tile max (log2-domain; QK^T pre-scaled in gemmqkv)
    float mx = -__builtin_inff();
#pragma unroll
    for (int n = 0; n < 4; n++) {
      const float* mkp = &mk[n].x;
#pragma unroll
      for (int j = 0; j < 4; j++) {
        float s = sacc[n][j] + mkp[j];
        sacc[n][j] = s;
        mx = fmaxf(mx, s);
      }
    }
    mx = fmaxf(mx, __shfl_xor(mx, 16));
    mx = fmaxf(mx, __shfl_xor(mx, 32));

    // T13 defer-max: skip rescale when growth bounded (P <= 2^11.54 = e^8)
    int full = !__all(mx - mrun <= THR2);

    float alpha = 1.f;
    if (full) {
      float mnew = fmaxf(mrun, mx);
      alpha = __builtin_amdgcn_exp2f(mrun - mnew);
      mrun = mnew;
    }
    float rs = 0.f;
#pragma unroll
    for (int n = 0; n < 4; n++) {
#pragma unroll
      for (int j = 0; j < 4; j++) {
        float p = __builtin_amdgcn_exp2f(sacc[n][j] - mrun);
        sacc[n][j] = p;
        rs += p;
      }
    }
    rs += __shfl_xor(rs, 16);
    rs += __shfl_xor(rs, 32);
    lrun = lrun * alpha + rs;

    // P -> LDS (keys contiguous; same-wave rows only, no barrier needed)
#pragma unroll
    for (int n = 0; n < 4; n++) {
      bf16x4 pk = {(__bf16)sacc[n][0], (__bf16)sacc[n][1],
                   (__bf16)sacc[n][2], (__bf16)sacc[n][3]};
      int g8 = (n * 2 + (lh >> 1)) ^ rx;
      *(bf16x4*)&Ps[prow * 64 + (g8 << 3) + ((lh & 1) << 2)] = pk;
    }

    if (full) {
#pragma unroll
      for (int jj = 0; jj < 4; jj++) {
        float a = __shfl(alpha, lh * 4 + jj);
#pragma unroll
        for (int n = 0; n < 4; n++) oacc[n][jj] *= a;
      }
    }

    // O += P V
#pragma unroll
    for (int ks = 0; ks < 2; ++ks) {
      bf16x8 pf = *(const bf16x8*)&Ps[prow * 64 + (((ks * 4 + lh) ^ rx) << 3)];
      bf16x8 vf[4];
#pragma unroll
      for (int n = 0; n < 4; n++)
        vf[n] = *(const bf16x8*)&Vs[bb][(n * 16 + lr) * 64 + (((ks * 4 + lh) ^ rx) << 3)];
#pragma unroll
      for (int n = 0; n < 4; n++)
        oacc[n] = __builtin_amdgcn_mfma_f32_16x16x32_bf16(pf, vf[n], oacc[n], 0, 0, 0);
    }
  }

  if (isLocal) {
#pragma unroll
    for (int jj = 0; jj < 4; jj++) {
      float inv = 1.f / __shfl(lrun, lh * 4 + jj);
      int row = q0 + wid * 16 + lh * 4 + jj;
#pragma unroll
      for (int n = 0; n < 4; n++)
        AL[((long)b * SEQ + row) * 1024 + h * 64 + n * 16 + lr] =
            (__bf16)(oacc[n][jj] * inv);
    }
  } else {
    float* Op = Opart + (long)pidx * (64 * 64);
    int srow = wid * 16 + lr;
    if (lh == 0) {
      Ml[pidx * 128 + srow] = mrun;
      Ml[pidx * 128 + 64 + srow] = lrun;
    }
#pragma unroll
    for (int jj = 0; jj < 4; jj++) {
      int row = wid * 16 + lh * 4 + jj;
#pragma unroll
      for (int n = 0; n < 4; n++) Op[row * 64 + n * 16 + lr] = oacc[n][jj];
    }
  }
}

// ------- combine global-attn partials (64-row partials, exp2-domain) -------
__global__ __launch_bounds__(256) void combine_global(
    const float* __restrict__ Opart, const float* __restrict__ Ml,
    __bf16* __restrict__ AG) {
  int uh = blockIdx.x;                // unit*2 + row-half, 0..63
  int unit = uh >> 1, rh = uh & 1;
  int b = unit >> 4, h = unit & 15;
  int t = threadIdx.x;
  int row = t >> 2, seg = t & 3, f0 = seg * 16;

  float mstar = -__builtin_inff();
#pragma unroll
  for (int c = 0; c < NCHUNK; ++c)
    mstar = fmaxf(mstar, Ml[(uh * NCHUNK + c) * 128 + row]);

  float L = 0.f;
  f32x4 acc[4];
#pragma unroll
  for (int k = 0; k < 4; k++) acc[k] = (f32x4){0.f, 0.f, 0.f, 0.f};

  for (int c = 0; c < NCHUNK; ++c) {
    int idx = uh * NCHUNK + c;
    float w = __builtin_amdgcn_exp2f(Ml[idx * 128 + row] - mstar);
    L += w * Ml[idx * 128 + 64 + row];
    const f32x4* src = (const f32x4*)(Opart + ((long)idx * 64 + row) * 64 + f0);
#pragma unroll
    for (int k = 0; k < 4; k++) acc[k] += src[k] * w;
  }
  float inv = 1.f / L;
  __bf16* dst = AG + ((long)b * GQ + rh * 64 + row) * 1024 + h * 64 + f0;
#pragma unroll
  for (int k = 0; k < 4; k++) {
    bf16x4 o = {(__bf16)(acc[k][0] * inv), (__bf16)(acc[k][1] * inv),
                (__bf16)(acc[k][2] * inv), (__bf16)(acc[k][3] * inv)};
    *(bf16x4*)(dst + k * 4) = o;
  }
}

extern "C" void kernel_launch(void* const* d_in, const int* in_sizes, int n_in,
                              void* d_out, int out_size, void* d_ws, size_t ws_size,
                              hipStream_t stream) {
  const float* Xt = (const float*)d_in[0];
  const float* Xg = (const float*)d_in[1];
  const float* Msk = (const float*)d_in[2];
  const float* Wq = (const float*)d_in[3];
  const float* Wk = (const float*)d_in[4];
  const float* Wv = (const float*)d_in[5];
  const float* Wo = (const float*)d_in[6];

  float* outF = (float*)d_out;

  char* ws = (char*)d_ws;
  __bf16* Wb = (__bf16*)ws;  ws += (size_t)4 * DM * DM * 2;
  __bf16* XB = (__bf16*)ws;  ws += (size_t)8448 * DM * 2;
  __bf16* Qt = (__bf16*)ws;  ws += (size_t)2 * SEQ * DM * 2;
  __bf16* Kt = (__bf16*)ws;  ws += (size_t)2 * SEQ * DM * 2;
  __bf16* VtT = (__bf16*)ws; ws += (size_t)2 * SEQ * DM * 2;
  __bf16* Qg = (__bf16*)ws;  ws += (size_t)2 * GQ * DM * 2;
  __bf16* Kg = (__bf16*)ws;  ws += (size_t)2 * GQ * DM * 2;
  __bf16* VgT = (__bf16*)ws; ws += (size_t)2 * GQ * DM * 2;
  __bf16* AB = (__bf16*)ws;  ws += (size_t)8448 * DM * 2;

  __bf16* AL = AB;
  __bf16* AG = AB + (size_t)8192 * DM;

  // 704 partials x (64x64 f32) + Ml 704 x 128 f32 -> lives in XB scratch
  float* Opart = (float*)XB;
  float* Ml = Opart + (long)32 * 2 * NCHUNK * 64 * 64;

  // merged casts: 4096 (weights) + 8192 (token X) + 256 (global X)
  cast_all<<<dim3(12544), 256, 0, stream>>>(Wq, Wk, Wv, Wo, Xt, Xg, Wb, XB);

  // QKV projection: M=8448 (132 x 64), N=3072 (24 x 128) -> 3168 blocks
  gemmqkv<<<dim3(3168), 256, 0, stream>>>(XB, Wb, Qt, Kt, VtT, Qg, Kg, VgT, 24);

  // attention: 2048 local (64 q-rows) + 704 global half-row chunk blocks
  attn_kernel<<<dim3(2048 + 32 * 2 * NCHUNK), 256, 0, stream>>>(
      Qt, Qg, Kg, VgT, Kt, VtT, Msk, AL, Opart, Ml);

  combine_global<<<dim3(64), 256, 0, stream>>>(Opart, Ml, AG);

  // Output projection: M=8448, N=1024 -> 66 x 8 tiles
  gemm128<<<dim3(528), 256, 0, stream>>>(AB, Wb + (size_t)3 * DM * DM, outF, 8);
}

// Round 16
// 185.216 us; speedup vs baseline: 1.0368x; 1.0368x over previous
//
#include <hip/hip_runtime.h>
#include <hip/hip_bf16.h>
#include <stdint.h>

typedef __attribute__((ext_vector_type(8))) __bf16 bf16x8;
typedef __attribute__((ext_vector_type(4))) __bf16 bf16x4;
typedef __attribute__((ext_vector_type(4))) float f32x4;

#define HN 16
#define DM 1024
#define GQ 128
#define SEQ 4096
#define BLK 512
#define SCALE 0.125f
#define LOG2E 1.44269504f
#define QSCALE2 0.18033688f  /* SCALE * log2(e) */
#define THR2 11.5415f        /* 8 * log2(e): same e^8 bound on P */
#define NCHUNK 11

#define GLL16(g, l) __builtin_amdgcn_global_load_lds( \
    (__attribute__((address_space(1))) void*)(g), \
    (__attribute__((address_space(3))) void*)(l), 16, 0, 0)

// ---------------- merged cast: weights + token X + global X ----------------
__global__ void cast_all(const float* __restrict__ w0, const float* __restrict__ w1,
                         const float* __restrict__ w2, const float* __restrict__ w3,
                         const float* __restrict__ Xt, const float* __restrict__ Xg,
                         __bf16* __restrict__ Wb, __bf16* __restrict__ XB) {
  int bid = blockIdx.x;
  const float* src;
  __bf16* dst;
  int t;
  if (bid < 4096) {                      // 4 weights x 1024 blocks
    int wi = bid >> 10;
    const float* srcs[4] = {w0, w1, w2, w3};
    src = srcs[wi];
    t = (bid & 1023) * 256 + threadIdx.x;
    dst = Wb + (size_t)wi * (size_t)(DM * DM);
  } else if (bid < 4096 + 8192) {        // token hidden states
    src = Xt;
    t = (bid - 4096) * 256 + threadIdx.x;
    dst = XB;
  } else {                               // global hidden states (256 blocks)
    src = Xg;
    t = (bid - 12288) * 256 + threadIdx.x;
    dst = XB + (size_t)8192 * DM;
  }
  float4 v = ((const float4*)src)[t];
  bf16x4 o = {(__bf16)v.x, (__bf16)v.y, (__bf16)v.z, (__bf16)v.w};
  ((bf16x4*)dst)[t] = o;
}

// ---------------- 128x128x64 QKV GEMM (round-14, proven) -------------------
// Q output pre-multiplied by SCALE*log2e so attn's QK^T lands in log2-domain.
// 64x128 M-split REVERTED (round 15: doubled B traffic -> HBM-bound, +11 us).
__global__ __launch_bounds__(256, 4) void gemmqkv(
    const __bf16* __restrict__ A, const __bf16* __restrict__ W,
    __bf16* __restrict__ Qt, __bf16* __restrict__ Kt, __bf16* __restrict__ VtT,
    __bf16* __restrict__ Qg, __bf16* __restrict__ Kg, __bf16* __restrict__ VgT,
    int NT) {
  __shared__ __bf16 S[2 * 128 * 64];  // K-loop: As|Bs ; epilogue: 128x128 C
  __bf16* As = S;
  __bf16* Bs = S + 128 * 64;
  int tid = threadIdx.x;
  int lane = tid & 63, wid = tid >> 6;
  int lr = lane & 15, lh = lane >> 4;
  int wm = wid >> 1, wn = wid & 1;

  int nwg = gridDim.x;
  int q = nwg >> 3, r = nwg & 7;
  int xcd = blockIdx.x & 7, loc = blockIdx.x >> 3;
  int swz = (xcd < r ? xcd * (q + 1) : r * (q + 1) + (xcd - r) * q) + loc;
  int bm = swz / NT, bn = swz - bm * NT;
  long m0 = (long)bm * 128, n0 = (long)bn * 128;
  const __bf16* Ab = A + m0 * 1024;
  const __bf16* Wb2 = W + n0 * 1024;

  int srow = tid >> 3;
  int scol = (((tid & 7) ^ (srow & 7)) << 3);

  f32x4 acc[4][4];
#pragma unroll
  for (int i = 0; i < 4; ++i)
#pragma unroll
    for (int j = 0; j < 4; ++j) acc[i][j] = (f32x4){0.f, 0.f, 0.f, 0.f};

#pragma unroll 1
  for (int kt = 0; kt < 16; ++kt) {
    int k0 = kt * 64;
#pragma unroll
    for (int c = 0; c < 4; ++c) {
      int row = srow + c * 32;
      GLL16(Ab + (long)row * 1024 + k0 + scol, &As[(c * 256 + tid) * 8]);
    }
#pragma unroll
    for (int c = 0; c < 4; ++c) {
      int row = srow + c * 32;
      GLL16(Wb2 + (long)row * 1024 + k0 + scol, &Bs[(c * 256 + tid) * 8]);
    }
    asm volatile("s_waitcnt vmcnt(0)" ::: "memory");
    __syncthreads();

#pragma unroll
    for (int ks = 0; ks < 2; ++ks) {
      bf16x8 af[4], bfr[4];
#pragma unroll
      for (int i = 0; i < 4; ++i) {
        int rr = wm * 64 + i * 16 + lr;
        af[i] = *(const bf16x8*)&As[rr * 64 + (((ks * 4 + lh) ^ (rr & 7)) << 3)];
        int cc = wn * 64 + i * 16 + lr;
        bfr[i] = *(const bf16x8*)&Bs[cc * 64 + (((ks * 4 + lh) ^ (cc & 7)) << 3)];
      }
#pragma unroll
      for (int i = 0; i < 4; ++i)
#pragma unroll
        for (int j = 0; j < 4; ++j)
          acc[i][j] = __builtin_amdgcn_mfma_f32_16x16x32_bf16(af[i], bfr[j],
                                                              acc[i][j], 0, 0, 0);
    }
    __syncthreads();
  }

  int z = (int)(n0 >> 10);           // 0=Q 1=K 2=V (constant per block)
  float qs = (z == 0) ? QSCALE2 : 1.0f;

  // ---- epilogue: C -> LDS (swizzled) -> coalesced stores ----
  __bf16* Cl = S;
#pragma unroll
  for (int i = 0; i < 4; ++i)
#pragma unroll
    for (int j = 0; j < 4; ++j) {
      int col = wn * 64 + j * 16 + lr;
      int cg = col >> 3, ce = col & 7;
#pragma unroll
      for (int jj = 0; jj < 4; ++jj) {
        int row = wm * 64 + i * 16 + lh * 4 + jj;
        Cl[row * 128 + ((cg ^ (row & 7)) << 3) + ce] = (__bf16)(acc[i][j][jj] * qs);
      }
    }
  __syncthreads();

  int hbase = ((int)n0 & 1023) >> 6;
  int tok = m0 < 8192;

  if (z < 2) {
    int row = tid >> 1, seg = tid & 1;
    long grow = m0 + row;
    __bf16* dst;
    if (tok) {
      long bh = (grow >> 12) * HN + hbase + seg;
      dst = (z == 0 ? Qt : Kt) + (bh * SEQ + (grow & 4095)) * 64;
    } else {
      int gr = (int)(grow - 8192);
      long bh = (long)(gr >> 7) * HN + hbase + seg;
      dst = (z == 0 ? Qg : Kg) + (bh * GQ + (gr & 127)) * 64;
    }
#pragma unroll
    for (int g = 0; g < 8; ++g) {
      int g8 = seg * 8 + g;
      bf16x8 v = *(const bf16x8*)&Cl[row * 128 + ((g8 ^ (row & 7)) << 3)];
      *(bf16x8*)(dst + g * 8) = v;
    }
  } else {
    int colL = tid >> 1, half = tid & 1;
    int h = hbase + (colL >> 6), f = colL & 63;
    int cg = colL >> 3, ce = colL & 7;
    __bf16* dst;
    if (tok) {
      long bh = (m0 >> 12) * HN + h;
      dst = VtT + (bh * 64 + f) * SEQ + (int)(m0 & 4095) + half * 64;
    } else {
      long gr0 = m0 - 8192;
      long bh = (gr0 >> 7) * HN + h;
      dst = VgT + (bh * 64 + f) * GQ + half * 64;
    }
#pragma unroll
    for (int c8 = 0; c8 < 8; ++c8) {
      bf16x8 v;
#pragma unroll
      for (int e = 0; e < 8; ++e) {
        int rr = half * 64 + c8 * 8 + e;
        v[e] = Cl[rr * 128 + ((cg ^ (rr & 7)) << 3) + ce];
      }
      *(bf16x8*)(dst + c8 * 8) = v;
    }
  }
}

// ---------------- 128x128x64 GEMM (round-3 proven) for output projection ---
__global__ __launch_bounds__(256, 4) void gemm128(
    const __bf16* __restrict__ A, const __bf16* __restrict__ W,
    float* __restrict__ Cf, int NT) {
  __shared__ __bf16 As[128 * 64];
  __shared__ __bf16 Bs[128 * 64];
  int tid = threadIdx.x;
  int lane = tid & 63, wid = tid >> 6;
  int lr = lane & 15, lh = lane >> 4;
  int wm = wid >> 1, wn = wid & 1;

  int nwg = gridDim.x;
  int q = nwg >> 3, r = nwg & 7;
  int xcd = blockIdx.x & 7, loc = blockIdx.x >> 3;
  int swz = (xcd < r ? xcd * (q + 1) : r * (q + 1) + (xcd - r) * q) + loc;
  int bm = swz / NT, bn = swz - bm * NT;
  long m0 = (long)bm * 128, n0 = (long)bn * 128;
  const __bf16* Ab = A + m0 * 1024;
  const __bf16* Wb2 = W + n0 * 1024;

  int srow = tid >> 3;
  int scol = (((tid & 7) ^ (srow & 7)) << 3);

  f32x4 acc[4][4];
#pragma unroll
  for (int i = 0; i < 4; ++i)
#pragma unroll
    for (int j = 0; j < 4; ++j) acc[i][j] = (f32x4){0.f, 0.f, 0.f, 0.f};

#pragma unroll 1
  for (int kt = 0; kt < 16; ++kt) {
    int k0 = kt * 64;
#pragma unroll
    for (int c = 0; c < 4; ++c) {
      int row = srow + c * 32;
      GLL16(Ab + (long)row * 1024 + k0 + scol, &As[(c * 256 + tid) * 8]);
    }
#pragma unroll
    for (int c = 0; c < 4; ++c) {
      int row = srow + c * 32;
      GLL16(Wb2 + (long)row * 1024 + k0 + scol, &Bs[(c * 256 + tid) * 8]);
    }
    asm volatile("s_waitcnt vmcnt(0)" ::: "memory");
    __syncthreads();

#pragma unroll
    for (int ks = 0; ks < 2; ++ks) {
      bf16x8 af[4], bfr[4];
#pragma unroll
      for (int i = 0; i < 4; ++i) {
        int rr = wm * 64 + i * 16 + lr;
        af[i] = *(const bf16x8*)&As[rr * 64 + (((ks * 4 + lh) ^ (rr & 7)) << 3)];
        int cc = wn * 64 + i * 16 + lr;
        bfr[i] = *(const bf16x8*)&Bs[cc * 64 + (((ks * 4 + lh) ^ (cc & 7)) << 3)];
      }
#pragma unroll
      for (int i = 0; i < 4; ++i)
#pragma unroll
        for (int j = 0; j < 4; ++j)
          acc[i][j] = __builtin_amdgcn_mfma_f32_16x16x32_bf16(af[i], bfr[j],
                                                              acc[i][j], 0, 0, 0);
    }
    __syncthreads();
  }

#pragma unroll
  for (int i = 0; i < 4; ++i) {
    long row0 = m0 + wm * 64 + i * 16 + lh * 4;
#pragma unroll
    for (int j = 0; j < 4; ++j) {
      int col = (int)n0 + wn * 64 + j * 16 + lr;
#pragma unroll
      for (int jj = 0; jj < 4; ++jj) Cf[(row0 + jj) * 1024 + col] = acc[i][j][jj];
    }
  }
}

// --- fused flash attention: 64 q-rows/block (round-14, proven) --------------
__global__ __launch_bounds__(256) void attn_kernel(
    const __bf16* __restrict__ Qt, const __bf16* __restrict__ Qg,
    const __bf16* __restrict__ Kg, const __bf16* __restrict__ VgT,
    const __bf16* __restrict__ Kt, const __bf16* __restrict__ VtT,
    const float* __restrict__ mask,
    __bf16* __restrict__ AL, float* __restrict__ Opart, float* __restrict__ Ml) {
  __shared__ __bf16 Ks[2][64 * 64];
  __shared__ __bf16 Vs[2][64 * 64];
  __shared__ __bf16 Ps[64 * 64];

  int hw = blockIdx.x;
  int bid = ((hw >> 6) << 6) + ((hw & 7) << 3) + ((hw >> 3) & 7);

  int tid = threadIdx.x, wid = tid >> 6, lane = tid & 63;
  int lr = lane & 15, lh = lane >> 4;

  int isLocal = bid < 2048;
  int unit, q0, tgoff, tokbase, ntiles, pidx = 0;
  if (isLocal) {
    unit = bid >> 6;
    q0 = (bid & 63) << 6;           // 64 q-rows per block
    tgoff = 0;
    tokbase = q0 & ~(BLK - 1);
    ntiles = 10;
  } else {
    int x = bid - 2048;
    int uh = x / NCHUNK;            // unit*2 + row-half
    int chunk = x - uh * NCHUNK;
    unit = uh >> 1;
    q0 = (uh & 1) << 6;             // 0 or 64 within the 128 global q-rows
    tgoff = chunk * 6;
    tokbase = 0;
    ntiles = 6;
    pidx = x;
  }
  int b = unit >> 4, h = unit & 15;
  long bh = unit;
  const __bf16* Qbase = isLocal ? Qt + (bh * SEQ + q0) * 64
                                : Qg + (bh * GQ + q0) * 64;

  bf16x8 qf[2];
#pragma unroll
  for (int ks = 0; ks < 2; ks++)
    qf[ks] = *(const bf16x8*)&Qbase[(wid * 16 + lr) * 64 + ks * 32 + lh * 8];

  float mrun = -__builtin_inff(), lrun = 0.f;
  f32x4 oacc[4];
#pragma unroll
  for (int n = 0; n < 4; n++) oacc[n] = (f32x4){0.f, 0.f, 0.f, 0.f};

  int rx = lane & 7;  // 3-bit read-side granule XOR (read rows = lr mod 8)
  int scol = (((lane & 7) ^ (lane >> 3)) << 3);
  int prow = wid * 16 + lr;  // P row (prow&7 == lr&7)

  auto stage = [&](int t, int bb) {
    int tg = t + tgoff;
    int glob = tg < 2;
    int kpos0 = glob ? tg * 64 : tokbase + (tg - 2) * 64;
    const __bf16* Kp = glob ? Kg + (bh * GQ + kpos0) * 64 : Kt + (bh * SEQ + kpos0) * 64;
    const __bf16* Vp = glob ? VgT + bh * 64 * GQ + kpos0 : VtT + bh * 64 * SEQ + kpos0;
    long vstr = glob ? GQ : SEQ;
#pragma unroll
    for (int s = 0; s < 2; ++s) {
      int r = s * 32 + wid * 8 + (lane >> 3);  // r&7 == lane>>3
      GLL16(Kp + (long)r * 64 + scol, &Ks[bb][(s * 256 + wid * 64) * 8]);
      GLL16(Vp + (long)r * vstr + scol, &Vs[bb][(s * 256 + wid * 64) * 8]);
    }
  };

  stage(0, 0);

  for (int t = 0; t < ntiles; ++t) {
    int bb = t & 1;
    int tg = t + tgoff;
    int glob = tg < 2;
    int kpos0 = glob ? tg * 64 : tokbase + (tg - 2) * 64;

    __syncthreads();
    if (t + 1 < ntiles) stage(t + 1, bb ^ 1);

    f32x4 sacc[4];
#pragma unroll
    for (int n = 0; n < 4; n++) sacc[n] = (f32x4){0.f, 0.f, 0.f, 0.f};
#pragma unroll
    for (int ks = 0; ks < 2; ++ks) {
      bf16x8 kf[4];
#pragma unroll
      for (int n = 0; n < 4; n++)
        kf[n] = *(const bf16x8*)&Ks[bb][(n * 16 + lr) * 64 + (((ks * 4 + lh) ^ rx) << 3)];
#pragma unroll
      for (int n = 0; n < 4; n++)
        sacc[n] = __builtin_amdgcn_mfma_f32_16x16x32_bf16(kf[n], qf[ks], sacc[n], 0, 0, 0);
    }

    float4 mk[4];
    if (glob) {
#pragma unroll
      for (int n = 0; n < 4; n++) mk[n] = (float4){0.f, 0.f, 0.f, 0.f};
    } else {
#pragma unroll
      for (int n = 0; n < 4; n++) {
        float4 t4 = *(const float4*)&mask[(long)b * SEQ + kpos0 + n * 16 + lh * 4];
        mk[n] = (float4){t4.x * LOG2E, t4.y * LOG2E, t4.z * LOG2E, t4.w * LOG2E};
      }
    }

    // mask add, per-row tile max (log2-domain; QK^T pre-scaled in gemmqkv)
    float mx = -__builtin_inff();
#pragma unroll
    for (int n = 0; n < 4; n++) {
      const float* mkp = &mk[n].x;
#pragma unroll
      for (int j = 0; j < 4; j++) {
        float s = sacc[n][j] + mkp[j];
        sacc[n][j] = s;
        mx = fmaxf(mx, s);
      }
    }
    mx = fmaxf(mx, __shfl_xor(mx, 16));
    mx = fmaxf(mx, __shfl_xor(mx, 32));

    // T13 defer-max: skip rescale when growth bounded (P <= 2^11.54 = e^8)
    int full = !__all(mx - mrun <= THR2);

    float alpha = 1.f;
    if (full) {
      float mnew = fmaxf(mrun, mx);
      alpha = __builtin_amdgcn_exp2f(mrun - mnew);
      mrun = mnew;
    }
    float rs = 0.f;
#pragma unroll
    for (int n = 0; n < 4; n++) {
#pragma unroll
      for (int j = 0; j < 4; j++) {
        float p = __builtin_amdgcn_exp2f(sacc[n][j] - mrun);
        sacc[n][j] = p;
        rs += p;
      }
    }
    rs += __shfl_xor(rs, 16);
    rs += __shfl_xor(rs, 32);
    lrun = lrun * alpha + rs;

    // P -> LDS (keys contiguous; same-wave rows only, no barrier needed)
#pragma unroll
    for (int n = 0; n < 4; n++) {
      bf16x4 pk = {(__bf16)sacc[n][0], (__bf16)sacc[n][1],
                   (__bf16)sacc[n][2], (__bf16)sacc[n][3]};
      int g8 = (n * 2 + (lh >> 1)) ^ rx;
      *(bf16x4*)&Ps[prow * 64 + (g8 << 3) + ((lh & 1) << 2)] = pk;
    }

    if (full) {
#pragma unroll
      for (int jj = 0; jj < 4; jj++) {
        float a = __shfl(alpha, lh * 4 + jj);
#pragma unroll
        for (int n = 0; n < 4; n++) oacc[n][jj] *= a;
      }
    }

    // O += P V
#pragma unroll
    for (int ks = 0; ks < 2; ++ks) {
      bf16x8 pf = *(const bf16x8*)&Ps[prow * 64 + (((ks * 4 + lh) ^ rx) << 3)];
      bf16x8 vf[4];
#pragma unroll
      for (int n = 0; n < 4; n++)
        vf[n] = *(const bf16x8*)&Vs[bb][(n * 16 + lr) * 64 + (((ks * 4 + lh) ^ rx) << 3)];
#pragma unroll
      for (int n = 0; n < 4; n++)
        oacc[n] = __builtin_amdgcn_mfma_f32_16x16x32_bf16(pf, vf[n], oacc[n], 0, 0, 0);
    }
  }

  if (isLocal) {
#pragma unroll
    for (int jj = 0; jj < 4; jj++) {
      float inv = 1.f / __shfl(lrun, lh * 4 + jj);
      int row = q0 + wid * 16 + lh * 4 + jj;
#pragma unroll
      for (int n = 0; n < 4; n++)
        AL[((long)b * SEQ + row) * 1024 + h * 64 + n * 16 + lr] =
            (__bf16)(oacc[n][jj] * inv);
    }
  } else {
    float* Op = Opart + (long)pidx * (64 * 64);
    int srow = wid * 16 + lr;
    if (lh == 0) {
      Ml[pidx * 128 + srow] = mrun;
      Ml[pidx * 128 + 64 + srow] = lrun;
    }
#pragma unroll
    for (int jj = 0; jj < 4; jj++) {
      int row = wid * 16 + lh * 4 + jj;
#pragma unroll
      for (int n = 0; n < 4; n++) Op[row * 64 + n * 16 + lr] = oacc[n][jj];
    }
  }
}

// ------- combine global-attn partials (64-row partials, exp2-domain) -------
__global__ __launch_bounds__(256) void combine_global(
    const float* __restrict__ Opart, const float* __restrict__ Ml,
    __bf16* __restrict__ AG) {
  int uh = blockIdx.x;                // unit*2 + row-half, 0..63
  int unit = uh >> 1, rh = uh & 1;
  int b = unit >> 4, h = unit & 15;
  int t = threadIdx.x;
  int row = t >> 2, seg = t & 3, f0 = seg * 16;

  float mstar = -__builtin_inff();
#pragma unroll
  for (int c = 0; c < NCHUNK; ++c)
    mstar = fmaxf(mstar, Ml[(uh * NCHUNK + c) * 128 + row]);

  float L = 0.f;
  f32x4 acc[4];
#pragma unroll
  for (int k = 0; k < 4; k++) acc[k] = (f32x4){0.f, 0.f, 0.f, 0.f};

  for (int c = 0; c < NCHUNK; ++c) {
    int idx = uh * NCHUNK + c;
    float w = __builtin_amdgcn_exp2f(Ml[idx * 128 + row] - mstar);
    L += w * Ml[idx * 128 + 64 + row];
    const f32x4* src = (const f32x4*)(Opart + ((long)idx * 64 + row) * 64 + f0);
#pragma unroll
    for (int k = 0; k < 4; k++) acc[k] += src[k] * w;
  }
  float inv = 1.f / L;
  __bf16* dst = AG + ((long)b * GQ + rh * 64 + row) * 1024 + h * 64 + f0;
#pragma unroll
  for (int k = 0; k < 4; k++) {
    bf16x4 o = {(__bf16)(acc[k][0] * inv), (__bf16)(acc[k][1] * inv),
                (__bf16)(acc[k][2] * inv), (__bf16)(acc[k][3] * inv)};
    *(bf16x4*)(dst + k * 4) = o;
  }
}

extern "C" void kernel_launch(void* const* d_in, const int* in_sizes, int n_in,
                              void* d_out, int out_size, void* d_ws, size_t ws_size,
                              hipStream_t stream) {
  const float* Xt = (const float*)d_in[0];
  const float* Xg = (const float*)d_in[1];
  const float* Msk = (const float*)d_in[2];
  const float* Wq = (const float*)d_in[3];
  const float* Wk = (const float*)d_in[4];
  const float* Wv = (const float*)d_in[5];
  const float* Wo = (const float*)d_in[6];

  float* outF = (float*)d_out;

  char* ws = (char*)d_ws;
  __bf16* Wb = (__bf16*)ws;  ws += (size_t)4 * DM * DM * 2;
  __bf16* XB = (__bf16*)ws;  ws += (size_t)8448 * DM * 2;
  __bf16* Qt = (__bf16*)ws;  ws += (size_t)2 * SEQ * DM * 2;
  __bf16* Kt = (__bf16*)ws;  ws += (size_t)2 * SEQ * DM * 2;
  __bf16* VtT = (__bf16*)ws; ws += (size_t)2 * SEQ * DM * 2;
  __bf16* Qg = (__bf16*)ws;  ws += (size_t)2 * GQ * DM * 2;
  __bf16* Kg = (__bf16*)ws;  ws += (size_t)2 * GQ * DM * 2;
  __bf16* VgT = (__bf16*)ws; ws += (size_t)2 * GQ * DM * 2;
  __bf16* AB = (__bf16*)ws;  ws += (size_t)8448 * DM * 2;

  __bf16* AL = AB;
  __bf16* AG = AB + (size_t)8192 * DM;

  // 704 partials x (64x64 f32) + Ml 704 x 128 f32 -> lives in XB scratch
  float* Opart = (float*)XB;
  float* Ml = Opart + (long)32 * 2 * NCHUNK * 64 * 64;

  // merged casts: 4096 (weights) + 8192 (token X) + 256 (global X)
  cast_all<<<dim3(12544), 256, 0, stream>>>(Wq, Wk, Wv, Wo, Xt, Xg, Wb, XB);

  // QKV projection: M=8448, N=3072 -> 66 x 24 tiles (round-14 proven)
  gemmqkv<<<dim3(1584), 256, 0, stream>>>(XB, Wb, Qt, Kt, VtT, Qg, Kg, VgT, 24);

  // attention: 2048 local (64 q-rows) + 704 global half-row chunk blocks
  attn_kernel<<<dim3(2048 + 32 * 2 * NCHUNK), 256, 0, stream>>>(
      Qt, Qg, Kg, VgT, Kt, VtT, Msk, AL, Opart, Ml);

  combine_global<<<dim3(64), 256, 0, stream>>>(Opart, Ml, AG);

  // Output projection: M=8448, N=1024 -> 66 x 8 tiles
  gemm128<<<dim3(528), 256, 0, stream>>>(AB, Wb + (size_t)3 * DM * DM, outF, 8);
}

// Round 17
// 184.706 us; speedup vs baseline: 1.0397x; 1.0028x over previous
//
#include <hip/hip_runtime.h>
#include <hip/hip_bf16.h>
#include <stdint.h>

typedef __attribute__((ext_vector_type(8))) __bf16 bf16x8;
typedef __attribute__((ext_vector_type(4))) __bf16 bf16x4;
typedef __attribute__((ext_vector_type(4))) float f32x4;

#define HN 16
#define DM 1024
#define GQ 128
#define SEQ 4096
#define BLK 512
#define SCALE 0.125f
#define LOG2E 1.44269504f
#define QSCALE2 0.18033688f  /* SCALE * log2(e) */
#define THR2 11.5415f        /* 8 * log2(e): same e^8 bound on P */
#define NCHUNK 11

#define GLL16(g, l) __builtin_amdgcn_global_load_lds( \
    (__attribute__((address_space(1))) void*)(g), \
    (__attribute__((address_space(3))) void*)(l), 16, 0, 0)

// ---------------- merged cast: weights + token X + global X ----------------
__global__ void cast_all(const float* __restrict__ w0, const float* __restrict__ w1,
                         const float* __restrict__ w2, const float* __restrict__ w3,
                         const float* __restrict__ Xt, const float* __restrict__ Xg,
                         __bf16* __restrict__ Wb, __bf16* __restrict__ XB) {
  int bid = blockIdx.x;
  const float* src;
  __bf16* dst;
  int t;
  if (bid < 4096) {                      // 4 weights x 1024 blocks
    int wi = bid >> 10;
    const float* srcs[4] = {w0, w1, w2, w3};
    src = srcs[wi];
    t = (bid & 1023) * 256 + threadIdx.x;
    dst = Wb + (size_t)wi * (size_t)(DM * DM);
  } else if (bid < 4096 + 8192) {        // token hidden states
    src = Xt;
    t = (bid - 4096) * 256 + threadIdx.x;
    dst = XB;
  } else {                               // global hidden states (256 blocks)
    src = Xg;
    t = (bid - 12288) * 256 + threadIdx.x;
    dst = XB + (size_t)8192 * DM;
  }
  float4 v = ((const float4*)src)[t];
  bf16x4 o = {(__bf16)v.x, (__bf16)v.y, (__bf16)v.z, (__bf16)v.w};
  ((bf16x4*)dst)[t] = o;
}

// ---------------- 128x128x64 QKV GEMM (round-14 body, 5 blocks/CU) ---------
// Q output pre-multiplied by SCALE*log2e so attn's QK^T lands in log2-domain.
// Residency: LDS 32 KB x 5 = 160 KiB exactly; VGPR 56 < floor(512/5)=102 ->
// 5 blocks/CU is resource-feasible; (256,5) lifts the 4-block cap. 1584
// blocks / 1280 resident = 1.24 generations (was 1.55 -> 55%-fill tail).
__global__ __launch_bounds__(256, 5) void gemmqkv(
    const __bf16* __restrict__ A, const __bf16* __restrict__ W,
    __bf16* __restrict__ Qt, __bf16* __restrict__ Kt, __bf16* __restrict__ VtT,
    __bf16* __restrict__ Qg, __bf16* __restrict__ Kg, __bf16* __restrict__ VgT,
    int NT) {
  __shared__ __bf16 S[2 * 128 * 64];  // K-loop: As|Bs ; epilogue: 128x128 C
  __bf16* As = S;
  __bf16* Bs = S + 128 * 64;
  int tid = threadIdx.x;
  int lane = tid & 63, wid = tid >> 6;
  int lr = lane & 15, lh = lane >> 4;
  int wm = wid >> 1, wn = wid & 1;

  int nwg = gridDim.x;
  int q = nwg >> 3, r = nwg & 7;
  int xcd = blockIdx.x & 7, loc = blockIdx.x >> 3;
  int swz = (xcd < r ? xcd * (q + 1) : r * (q + 1) + (xcd - r) * q) + loc;
  int bm = swz / NT, bn = swz - bm * NT;
  long m0 = (long)bm * 128, n0 = (long)bn * 128;
  const __bf16* Ab = A + m0 * 1024;
  const __bf16* Wb2 = W + n0 * 1024;

  int srow = tid >> 3;
  int scol = (((tid & 7) ^ (srow & 7)) << 3);

  f32x4 acc[4][4];
#pragma unroll
  for (int i = 0; i < 4; ++i)
#pragma unroll
    for (int j = 0; j < 4; ++j) acc[i][j] = (f32x4){0.f, 0.f, 0.f, 0.f};

#pragma unroll 1
  for (int kt = 0; kt < 16; ++kt) {
    int k0 = kt * 64;
#pragma unroll
    for (int c = 0; c < 4; ++c) {
      int row = srow + c * 32;
      GLL16(Ab + (long)row * 1024 + k0 + scol, &As[(c * 256 + tid) * 8]);
    }
#pragma unroll
    for (int c = 0; c < 4; ++c) {
      int row = srow + c * 32;
      GLL16(Wb2 + (long)row * 1024 + k0 + scol, &Bs[(c * 256 + tid) * 8]);
    }
    asm volatile("s_waitcnt vmcnt(0)" ::: "memory");
    __syncthreads();

#pragma unroll
    for (int ks = 0; ks < 2; ++ks) {
      bf16x8 af[4], bfr[4];
#pragma unroll
      for (int i = 0; i < 4; ++i) {
        int rr = wm * 64 + i * 16 + lr;
        af[i] = *(const bf16x8*)&As[rr * 64 + (((ks * 4 + lh) ^ (rr & 7)) << 3)];
        int cc = wn * 64 + i * 16 + lr;
        bfr[i] = *(const bf16x8*)&Bs[cc * 64 + (((ks * 4 + lh) ^ (cc & 7)) << 3)];
      }
#pragma unroll
      for (int i = 0; i < 4; ++i)
#pragma unroll
        for (int j = 0; j < 4; ++j)
          acc[i][j] = __builtin_amdgcn_mfma_f32_16x16x32_bf16(af[i], bfr[j],
                                                              acc[i][j], 0, 0, 0);
    }
    __syncthreads();
  }

  int z = (int)(n0 >> 10);           // 0=Q 1=K 2=V (constant per block)
  float qs = (z == 0) ? QSCALE2 : 1.0f;

  // ---- epilogue: C -> LDS (swizzled) -> coalesced stores ----
  __bf16* Cl = S;
#pragma unroll
  for (int i = 0; i < 4; ++i)
#pragma unroll
    for (int j = 0; j < 4; ++j) {
      int col = wn * 64 + j * 16 + lr;
      int cg = col >> 3, ce = col & 7;
#pragma unroll
      for (int jj = 0; jj < 4; ++jj) {
        int row = wm * 64 + i * 16 + lh * 4 + jj;
        Cl[row * 128 + ((cg ^ (row & 7)) << 3) + ce] = (__bf16)(acc[i][j][jj] * qs);
      }
    }
  __syncthreads();

  int hbase = ((int)n0 & 1023) >> 6;
  int tok = m0 < 8192;

  if (z < 2) {
    int row = tid >> 1, seg = tid & 1;
    long grow = m0 + row;
    __bf16* dst;
    if (tok) {
      long bh = (grow >> 12) * HN + hbase + seg;
      dst = (z == 0 ? Qt : Kt) + (bh * SEQ + (grow & 4095)) * 64;
    } else {
      int gr = (int)(grow - 8192);
      long bh = (long)(gr >> 7) * HN + hbase + seg;
      dst = (z == 0 ? Qg : Kg) + (bh * GQ + (gr & 127)) * 64;
    }
#pragma unroll
    for (int g = 0; g < 8; ++g) {
      int g8 = seg * 8 + g;
      bf16x8 v = *(const bf16x8*)&Cl[row * 128 + ((g8 ^ (row & 7)) << 3)];
      *(bf16x8*)(dst + g * 8) = v;
    }
  } else {
    int colL = tid >> 1, half = tid & 1;
    int h = hbase + (colL >> 6), f = colL & 63;
    int cg = colL >> 3, ce = colL & 7;
    __bf16* dst;
    if (tok) {
      long bh = (m0 >> 12) * HN + h;
      dst = VtT + (bh * 64 + f) * SEQ + (int)(m0 & 4095) + half * 64;
    } else {
      long gr0 = m0 - 8192;
      long bh = (gr0 >> 7) * HN + h;
      dst = VgT + (bh * 64 + f) * GQ + half * 64;
    }
#pragma unroll
    for (int c8 = 0; c8 < 8; ++c8) {
      bf16x8 v;
#pragma unroll
      for (int e = 0; e < 8; ++e) {
        int rr = half * 64 + c8 * 8 + e;
        v[e] = Cl[rr * 128 + ((cg ^ (rr & 7)) << 3) + ce];
      }
      *(bf16x8*)(dst + c8 * 8) = v;
    }
  }
}

// ---------------- 128x128x64 GEMM (round-3 proven) for output projection ---
__global__ __launch_bounds__(256, 4) void gemm128(
    const __bf16* __restrict__ A, const __bf16* __restrict__ W,
    float* __restrict__ Cf, int NT) {
  __shared__ __bf16 As[128 * 64];
  __shared__ __bf16 Bs[128 * 64];
  int tid = threadIdx.x;
  int lane = tid & 63, wid = tid >> 6;
  int lr = lane & 15, lh = lane >> 4;
  int wm = wid >> 1, wn = wid & 1;

  int nwg = gridDim.x;
  int q = nwg >> 3, r = nwg & 7;
  int xcd = blockIdx.x & 7, loc = blockIdx.x >> 3;
  int swz = (xcd < r ? xcd * (q + 1) : r * (q + 1) + (xcd - r) * q) + loc;
  int bm = swz / NT, bn = swz - bm * NT;
  long m0 = (long)bm * 128, n0 = (long)bn * 128;
  const __bf16* Ab = A + m0 * 1024;
  const __bf16* Wb2 = W + n0 * 1024;

  int srow = tid >> 3;
  int scol = (((tid & 7) ^ (srow & 7)) << 3);

  f32x4 acc[4][4];
#pragma unroll
  for (int i = 0; i < 4; ++i)
#pragma unroll
    for (int j = 0; j < 4; ++j) acc[i][j] = (f32x4){0.f, 0.f, 0.f, 0.f};

#pragma unroll 1
  for (int kt = 0; kt < 16; ++kt) {
    int k0 = kt * 64;
#pragma unroll
    for (int c = 0; c < 4; ++c) {
      int row = srow + c * 32;
      GLL16(Ab + (long)row * 1024 + k0 + scol, &As[(c * 256 + tid) * 8]);
    }
#pragma unroll
    for (int c = 0; c < 4; ++c) {
      int row = srow + c * 32;
      GLL16(Wb2 + (long)row * 1024 + k0 + scol, &Bs[(c * 256 + tid) * 8]);
    }
    asm volatile("s_waitcnt vmcnt(0)" ::: "memory");
    __syncthreads();

#pragma unroll
    for (int ks = 0; ks < 2; ++ks) {
      bf16x8 af[4], bfr[4];
#pragma unroll
      for (int i = 0; i < 4; ++i) {
        int rr = wm * 64 + i * 16 + lr;
        af[i] = *(const bf16x8*)&As[rr * 64 + (((ks * 4 + lh) ^ (rr & 7)) << 3)];
        int cc = wn * 64 + i * 16 + lr;
        bfr[i] = *(const bf16x8*)&Bs[cc * 64 + (((ks * 4 + lh) ^ (cc & 7)) << 3)];
      }
#pragma unroll
      for (int i = 0; i < 4; ++i)
#pragma unroll
        for (int j = 0; j < 4; ++j)
          acc[i][j] = __builtin_amdgcn_mfma_f32_16x16x32_bf16(af[i], bfr[j],
                                                              acc[i][j], 0, 0, 0);
    }
    __syncthreads();
  }

#pragma unroll
  for (int i = 0; i < 4; ++i) {
    long row0 = m0 + wm * 64 + i * 16 + lh * 4;
#pragma unroll
    for (int j = 0; j < 4; ++j) {
      int col = (int)n0 + wn * 64 + j * 16 + lr;
#pragma unroll
      for (int jj = 0; jj < 4; ++jj) Cf[(row0 + jj) * 1024 + col] = acc[i][j][jj];
    }
  }
}

// --- fused flash attention: 64 q-rows/block (round-14, proven) --------------
__global__ __launch_bounds__(256) void attn_kernel(
    const __bf16* __restrict__ Qt, const __bf16* __restrict__ Qg,
    const __bf16* __restrict__ Kg, const __bf16* __restrict__ VgT,
    const __bf16* __restrict__ Kt, const __bf16* __restrict__ VtT,
    const float* __restrict__ mask,
    __bf16* __restrict__ AL, float* __restrict__ Opart, float* __restrict__ Ml) {
  __shared__ __bf16 Ks[2][64 * 64];
  __shared__ __bf16 Vs[2][64 * 64];
  __shared__ __bf16 Ps[64 * 64];

  int hw = blockIdx.x;
  int bid = ((hw >> 6) << 6) + ((hw & 7) << 3) + ((hw >> 3) & 7);

  int tid = threadIdx.x, wid = tid >> 6, lane = tid & 63;
  int lr = lane & 15, lh = lane >> 4;

  int isLocal = bid < 2048;
  int unit, q0, tgoff, tokbase, ntiles, pidx = 0;
  if (isLocal) {
    unit = bid >> 6;
    q0 = (bid & 63) << 6;           // 64 q-rows per block
    tgoff = 0;
    tokbase = q0 & ~(BLK - 1);
    ntiles = 10;
  } else {
    int x = bid - 2048;
    int uh = x / NCHUNK;            // unit*2 + row-half
    int chunk = x - uh * NCHUNK;
    unit = uh >> 1;
    q0 = (uh & 1) << 6;             // 0 or 64 within the 128 global q-rows
    tgoff = chunk * 6;
    tokbase = 0;
    ntiles = 6;
    pidx = x;
  }
  int b = unit >> 4, h = unit & 15;
  long bh = unit;
  const __bf16* Qbase = isLocal ? Qt + (bh * SEQ + q0) * 64
                                : Qg + (bh * GQ + q0) * 64;

  bf16x8 qf[2];
#pragma unroll
  for (int ks = 0; ks < 2; ks++)
    qf[ks] = *(const bf16x8*)&Qbase[(wid * 16 + lr) * 64 + ks * 32 + lh * 8];

  float mrun = -__builtin_inff(), lrun = 0.f;
  f32x4 oacc[4];
#pragma unroll
  for (int n = 0; n < 4; n++) oacc[n] = (f32x4){0.f, 0.f, 0.f, 0.f};

  int rx = lane & 7;  // 3-bit read-side granule XOR (read rows = lr mod 8)
  int scol = (((lane & 7) ^ (lane >> 3)) << 3);
  int prow = wid * 16 + lr;  // P row (prow&7 == lr&7)

  auto stage = [&](int t, int bb) {
    int tg = t + tgoff;
    int glob = tg < 2;
    int kpos0 = glob ? tg * 64 : tokbase + (tg - 2) * 64;
    const __bf16* Kp = glob ? Kg + (bh * GQ + kpos0) * 64 : Kt + (bh * SEQ + kpos0) * 64;
    const __bf16* Vp = glob ? VgT + bh * 64 * GQ + kpos0 : VtT + bh * 64 * SEQ + kpos0;
    long vstr = glob ? GQ : SEQ;
#pragma unroll
    for (int s = 0; s < 2; ++s) {
      int r = s * 32 + wid * 8 + (lane >> 3);  // r&7 == lane>>3
      GLL16(Kp + (long)r * 64 + scol, &Ks[bb][(s * 256 + wid * 64) * 8]);
      GLL16(Vp + (long)r * vstr + scol, &Vs[bb][(s * 256 + wid * 64) * 8]);
    }
  };

  stage(0, 0);

  for (int t = 0; t < ntiles; ++t) {
    int bb = t & 1;
    int tg = t + tgoff;
    int glob = tg < 2;
    int kpos0 = glob ? tg * 64 : tokbase + (tg - 2) * 64;

    __syncthreads();
    if (t + 1 < ntiles) stage(t + 1, bb ^ 1);

    f32x4 sacc[4];
#pragma unroll
    for (int n = 0; n < 4; n++) sacc[n] = (f32x4){0.f, 0.f, 0.f, 0.f};
#pragma unroll
    for (int ks = 0; ks < 2; ++ks) {
      bf16x8 kf[4];
#pragma unroll
      for (int n = 0; n < 4; n++)
        kf[n] = *(const bf16x8*)&Ks[bb][(n * 16 + lr) * 64 + (((ks * 4 + lh) ^ rx) << 3)];
#pragma unroll
      for (int n = 0; n < 4; n++)
        sacc[n] = __builtin_amdgcn_mfma_f32_16x16x32_bf16(kf[n], qf[ks], sacc[n], 0, 0, 0);
    }

    float4 mk[4];
    if (glob) {
#pragma unroll
      for (int n = 0; n < 4; n++) mk[n] = (float4){0.f, 0.f, 0.f, 0.f};
    } else {
#pragma unroll
      for (int n = 0; n < 4; n++) {
        float4 t4 = *(const float4*)&mask[(long)b * SEQ + kpos0 + n * 16 + lh * 4];
        mk[n] = (float4){t4.x * LOG2E, t4.y * LOG2E, t4.z * LOG2E, t4.w * LOG2E};
      }
    }

    // mask add, per-row tile max (log2-domain; QK^T pre-scaled in gemmqkv)
    float mx = -__builtin_inff();
#pragma unroll
    for (int n = 0; n < 4; n++) {
      const float* mkp = &mk[n].x;
#pragma unroll
      for (int j = 0; j < 4; j++) {
        float s = sacc[n][j] + mkp[j];
        sacc[n][j] = s;
        mx = fmaxf(mx, s);
      }
    }
    mx = fmaxf(mx, __shfl_xor(mx, 16));
    mx = fmaxf(mx, __shfl_xor(mx, 32));

    // T13 defer-max: skip rescale when growth bounded (P <= 2^11.54 = e^8)
    int full = !__all(mx - mrun <= THR2);

    float alpha = 1.f;
    if (full) {
      float mnew = fmaxf(mrun, mx);
      alpha = __builtin_amdgcn_exp2f(mrun - mnew);
      mrun = mnew;
    }
    float rs = 0.f;
#pragma unroll
    for (int n = 0; n < 4; n++) {
#pragma unroll
      for (int j = 0; j < 4; j++) {
        float p = __builtin_amdgcn_exp2f(sacc[n][j] - mrun);
        sacc[n][j] = p;
        rs += p;
      }
    }
    rs += __shfl_xor(rs, 16);
    rs += __shfl_xor(rs, 32);
    lrun = lrun * alpha + rs;

    // P -> LDS (keys contiguous; same-wave rows only, no barrier needed)
#pragma unroll
    for (int n = 0; n < 4; n++) {
      bf16x4 pk = {(__bf16)sacc[n][0], (__bf16)sacc[n][1],
                   (__bf16)sacc[n][2], (__bf16)sacc[n][3]};
      int g8 = (n * 2 + (lh >> 1)) ^ rx;
      *(bf16x4*)&Ps[prow * 64 + (g8 << 3) + ((lh & 1) << 2)] = pk;
    }

    if (full) {
#pragma unroll
      for (int jj = 0; jj < 4; jj++) {
        float a = __shfl(alpha, lh * 4 + jj);
#pragma unroll
        for (int n = 0; n < 4; n++) oacc[n][jj] *= a;
      }
    }

    // O += P V
#pragma unroll
    for (int ks = 0; ks < 2; ++ks) {
      bf16x8 pf = *(const bf16x8*)&Ps[prow * 64 + (((ks * 4 + lh) ^ rx) << 3)];
      bf16x8 vf[4];
#pragma unroll
      for (int n = 0; n < 4; n++)
        vf[n] = *(const bf16x8*)&Vs[bb][(n * 16 + lr) * 64 + (((ks * 4 + lh) ^ rx) << 3)];
#pragma unroll
      for (int n = 0; n < 4; n++)
        oacc[n] = __builtin_amdgcn_mfma_f32_16x16x32_bf16(pf, vf[n], oacc[n], 0, 0, 0);
    }
  }

  if (isLocal) {
#pragma unroll
    for (int jj = 0; jj < 4; jj++) {
      float inv = 1.f / __shfl(lrun, lh * 4 + jj);
      int row = q0 + wid * 16 + lh * 4 + jj;
#pragma unroll
      for (int n = 0; n < 4; n++)
        AL[((long)b * SEQ + row) * 1024 + h * 64 + n * 16 + lr] =
            (__bf16)(oacc[n][jj] * inv);
    }
  } else {
    float* Op = Opart + (long)pidx * (64 * 64);
    int srow = wid * 16 + lr;
    if (lh == 0) {
      Ml[pidx * 128 + srow] = mrun;
      Ml[pidx * 128 + 64 + srow] = lrun;
    }
#pragma unroll
    for (int jj = 0; jj < 4; jj++) {
      int row = wid * 16 + lh * 4 + jj;
#pragma unroll
      for (int n = 0; n < 4; n++) Op[row * 64 + n * 16 + lr] = oacc[n][jj];
    }
  }
}

// ------- combine global-attn partials (64-row partials, exp2-domain) -------
__global__ __launch_bounds__(256) void combine_global(
    const float* __restrict__ Opart, const float* __restrict__ Ml,
    __bf16* __restrict__ AG) {
  int uh = blockIdx.x;                // unit*2 + row-half, 0..63
  int unit = uh >> 1, rh = uh & 1;
  int b = unit >> 4, h = unit & 15;
  int t = threadIdx.x;
  int row = t >> 2, seg = t & 3, f0 = seg * 16;

  float mstar = -__builtin_inff();
#pragma unroll
  for (int c = 0; c < NCHUNK; ++c)
    mstar = fmaxf(mstar, Ml[(uh * NCHUNK + c) * 128 + row]);

  float L = 0.f;
  f32x4 acc[4];
#pragma unroll
  for (int k = 0; k < 4; k++) acc[k] = (f32x4){0.f, 0.f, 0.f, 0.f};

  for (int c = 0; c < NCHUNK; ++c) {
    int idx = uh * NCHUNK + c;
    float w = __builtin_amdgcn_exp2f(Ml[idx * 128 + row] - mstar);
    L += w * Ml[idx * 128 + 64 + row];
    const f32x4* src = (const f32x4*)(Opart + ((long)idx * 64 + row) * 64 + f0);
#pragma unroll
    for (int k = 0; k < 4; k++) acc[k] += src[k] * w;
  }
  float inv = 1.f / L;
  __bf16* dst = AG + ((long)b * GQ + rh * 64 + row) * 1024 + h * 64 + f0;
#pragma unroll
  for (int k = 0; k < 4; k++) {
    bf16x4 o = {(__bf16)(acc[k][0] * inv), (__bf16)(acc[k][1] * inv),
                (__bf16)(acc[k][2] * inv), (__bf16)(acc[k][3] * inv)};
    *(bf16x4*)(dst + k * 4) = o;
  }
}

extern "C" void kernel_launch(void* const* d_in, const int* in_sizes, int n_in,
                              void* d_out, int out_size, void* d_ws, size_t ws_size,
                              hipStream_t stream) {
  const float* Xt = (const float*)d_in[0];
  const float* Xg = (const float*)d_in[1];
  const float* Msk = (const float*)d_in[2];
  const float* Wq = (const float*)d_in[3];
  const float* Wk = (const float*)d_in[4];
  const float* Wv = (const float*)d_in[5];
  const float* Wo = (const float*)d_in[6];

  float* outF = (float*)d_out;

  char* ws = (char*)d_ws;
  __bf16* Wb = (__bf16*)ws;  ws += (size_t)4 * DM * DM * 2;
  __bf16* XB = (__bf16*)ws;  ws += (size_t)8448 * DM * 2;
  __bf16* Qt = (__bf16*)ws;  ws += (size_t)2 * SEQ * DM * 2;
  __bf16* Kt = (__bf16*)ws;  ws += (size_t)2 * SEQ * DM * 2;
  __bf16* VtT = (__bf16*)ws; ws += (size_t)2 * SEQ * DM * 2;
  __bf16* Qg = (__bf16*)ws;  ws += (size_t)2 * GQ * DM * 2;
  __bf16* Kg = (__bf16*)ws;  ws += (size_t)2 * GQ * DM * 2;
  __bf16* VgT = (__bf16*)ws; ws += (size_t)2 * GQ * DM * 2;
  __bf16* AB = (__bf16*)ws;  ws += (size_t)8448 * DM * 2;

  __bf16* AL = AB;
  __bf16* AG = AB + (size_t)8192 * DM;

  // 704 partials x (64x64 f32) + Ml 704 x 128 f32 -> lives in XB scratch
  float* Opart = (float*)XB;
  float* Ml = Opart + (long)32 * 2 * NCHUNK * 64 * 64;

  // merged casts: 4096 (weights) + 8192 (token X) + 256 (global X)
  cast_all<<<dim3(12544), 256, 0, stream>>>(Wq, Wk, Wv, Wo, Xt, Xg, Wb, XB);

  // QKV projection: M=8448, N=3072 -> 66 x 24 tiles
  gemmqkv<<<dim3(1584), 256, 0, stream>>>(XB, Wb, Qt, Kt, VtT, Qg, Kg, VgT, 24);

  // attention: 2048 local (64 q-rows) + 704 global half-row chunk blocks
  attn_kernel<<<dim3(2048 + 32 * 2 * NCHUNK), 256, 0, stream>>>(
      Qt, Qg, Kg, VgT, Kt, VtT, Msk, AL, Opart, Ml);

  combine_global<<<dim3(64), 256, 0, stream>>>(Opart, Ml, AG);

  // Output projection: M=8448, N=1024 -> 66 x 8 tiles
  gemm128<<<dim3(528), 256, 0, stream>>>(AB, Wb + (size_t)3 * DM * DM, outF, 8);
}